// Round 2
// baseline (826.523 us; speedup 1.0000x reference)
//
#include <hip/hip_runtime.h>

// Problem constants (B=1)
#define SEQ     2048
#define HDIM    4096
#define NHEADS  32
#define NKVH    8
#define HEADD   128
#define QKV_LD  6144      // NH*HD + 2*NKV*HD
#define K_OFF   4096      // q region size (elements)
#define V_OFF   5120      // q+k region size

typedef __bf16 bf16x8 __attribute__((ext_vector_type(8)));
typedef float  f32x4  __attribute__((ext_vector_type(4)));

__device__ inline float bf2f(unsigned short u) {
  return __uint_as_float(((unsigned int)u) << 16);
}
__device__ inline unsigned short f2bf(float f) {
  unsigned int u = __float_as_uint(f);
  u += 0x7fff + ((u >> 16) & 1);   // round-to-nearest-even
  return (unsigned short)(u >> 16);
}
__device__ inline unsigned int pack2bf(float a, float b) {
  return (unsigned int)f2bf(a) | ((unsigned int)f2bf(b) << 16);
}

// ---------------------------------------------------------------------------
// C[m,n] = sum_k A[m,k] * B[n,k].  A: MxK (f32 or bf16, ld=lda); B: NxK f32
// (ld=K); C: bf16 or f32 (ld=ldc).  128x128 tile, BK=64, 4 waves in 2x2.
// ---------------------------------------------------------------------------
template<int A_BF16, int C_F32>
__global__ __launch_bounds__(256, 2) void gemm_bt(
    const void* __restrict__ Av,
    const float* __restrict__ B,
    void* __restrict__ Cv,
    int M, int N, int K, int lda, int ldc) {
  __shared__ __align__(16) unsigned short sA[128][72];   // +8 pad
  __shared__ __align__(16) unsigned short sB[128][72];

  const int t    = threadIdx.x;
  const int wave = t >> 6;
  const int lane = t & 63;
  const int lrow = lane & 15;   // m (A) / n (B) within 16-tile
  const int kgrp = lane >> 4;   // 0..3
  const int wm   = (wave >> 1) * 64;
  const int wn   = (wave & 1) * 64;
  const int m0   = blockIdx.x * 128;
  const int n0   = blockIdx.y * 128;

  const int ldr = t >> 3;        // 0..31: row within 32-row round
  const int c8  = (t & 7) * 8;   // 0..56: col (8 elements per thread)

  f32x4 acc[4][4];
  #pragma unroll
  for (int i = 0; i < 4; ++i)
    #pragma unroll
    for (int j = 0; j < 4; ++j)
      #pragma unroll
      for (int e = 0; e < 4; ++e) acc[i][j][e] = 0.f;

  for (int k0 = 0; k0 < K; k0 += 64) {
    __syncthreads();
    #pragma unroll
    for (int r = 0; r < 4; ++r) {
      int row = r * 32 + ldr;
      // ---- A tile ----
      if constexpr (A_BF16) {
        *(uint4*)&sA[row][c8] =
            *(const uint4*)((const unsigned short*)Av + (size_t)(m0 + row) * lda + k0 + c8);
      } else {
        const float* ap = (const float*)Av + (size_t)(m0 + row) * lda + k0 + c8;
        float4 x = *(const float4*)ap;
        float4 y = *(const float4*)(ap + 4);
        uint4 pk;
        pk.x = pack2bf(x.x, x.y);
        pk.y = pack2bf(x.z, x.w);
        pk.z = pack2bf(y.x, y.y);
        pk.w = pack2bf(y.z, y.w);
        *(uint4*)&sA[row][c8] = pk;
      }
      // ---- B tile (always f32) ----
      {
        const float* bp = B + (size_t)(n0 + row) * K + k0 + c8;
        float4 x = *(const float4*)bp;
        float4 y = *(const float4*)(bp + 4);
        uint4 pk;
        pk.x = pack2bf(x.x, x.y);
        pk.y = pack2bf(x.z, x.w);
        pk.z = pack2bf(y.x, y.y);
        pk.w = pack2bf(y.z, y.w);
        *(uint4*)&sB[row][c8] = pk;
      }
    }
    __syncthreads();
    #pragma unroll
    for (int ks = 0; ks < 2; ++ks) {
      bf16x8 af[4], bfm[4];
      #pragma unroll
      for (int i = 0; i < 4; ++i)
        af[i] = *(const bf16x8*)&sA[wm + i*16 + lrow][ks*32 + kgrp*8];
      #pragma unroll
      for (int j = 0; j < 4; ++j)
        bfm[j] = *(const bf16x8*)&sB[wn + j*16 + lrow][ks*32 + kgrp*8];
      #pragma unroll
      for (int i = 0; i < 4; ++i)
        #pragma unroll
        for (int j = 0; j < 4; ++j)
          acc[i][j] = __builtin_amdgcn_mfma_f32_16x16x32_bf16(af[i], bfm[j], acc[i][j], 0, 0, 0);
    }
  }

  // epilogue: C/D layout col=lane&15, row=(lane>>4)*4+reg
  #pragma unroll
  for (int i = 0; i < 4; ++i) {
    #pragma unroll
    for (int r = 0; r < 4; ++r) {
      int row = m0 + wm + i*16 + kgrp*4 + r;
      #pragma unroll
      for (int j = 0; j < 4; ++j) {
        int col = n0 + wn + j*16 + lrow;
        if constexpr (C_F32)
          ((float*)Cv)[(size_t)row * ldc + col] = acc[i][j][r];
        else
          ((unsigned short*)Cv)[(size_t)row * ldc + col] = f2bf(acc[i][j][r]);
      }
    }
  }
}

// ---------------------------------------------------------------------------
// RoPE in-place on q (heads 0..31) and k (heads 32..39) of the bf16 qkv buffer.
// ---------------------------------------------------------------------------
__global__ __launch_bounds__(256) void rope_kernel(
    unsigned short* __restrict__ qkv, const int* __restrict__ pos) {
  int tid  = blockIdx.x * 256 + threadIdx.x;
  int d    = tid & 63;
  int rh   = tid >> 6;
  int head = rh % 40;          // 0..31 q, 32..39 k (regions contiguous)
  int s    = rh / 40;
  if (s >= SEQ) return;
  unsigned short* p = qkv + (size_t)s * QKV_LD + head * 128 + d;
  float x1 = bf2f(p[0]);
  float x2 = bf2f(p[64]);
  // inv_freq = 100000^(-d/64) = exp(-d * ln(1e5)/64)
  float inv = __expf((float)d * -0.17988946039016608f);
  float ang = (float)pos[s] * inv;
  float sn, c;
  sincosf(ang, &sn, &c);
  p[0]  = f2bf(x1 * c - x2 * sn);
  p[64] = f2bf(x2 * c + x1 * sn);
}

// ---------------------------------------------------------------------------
// Causal flash attention with GQA. One block = (64 q-rows, 1 head), 4 waves;
// wave w owns q-rows [16w, 16w+16). KV iterated in 64-key tiles.
// Output written IN-PLACE into the Q region of qkv (each block's Q cells are
// read only by itself, before its own writes — disjoint across blocks).
// ---------------------------------------------------------------------------
__global__ __launch_bounds__(256, 2) void attn_fwd(
    unsigned short* __restrict__ qkv) {
  __shared__ __align__(16) unsigned short sK[64][136];    // [key][d], +8 pad
  __shared__ __align__(16) unsigned short sVt[128][72];   // [d][key] transposed
  __shared__ __align__(16) unsigned short sP[64][72];     // [q][key], +8 pad

  const int t    = threadIdx.x;
  const int wave = t >> 6;
  const int lane = t & 63;
  const int lrow = lane & 15;
  const int kgrp = lane >> 4;
  const int q0   = blockIdx.x * 64;
  const int h    = blockIdx.y;
  const int kvh  = h >> 2;                  // GROUPS = 4

  // Q fragments (A-operand): rows q0+16*wave+lrow, k = d
  bf16x8 qf[4];
  {
    const unsigned short* qrow =
        qkv + (size_t)(q0 + wave*16 + lrow) * QKV_LD + h * HEADD;
    #pragma unroll
    for (int ks = 0; ks < 4; ++ks)
      qf[ks] = *(const bf16x8*)(qrow + ks*32 + kgrp*8);
  }

  f32x4 of[8];
  #pragma unroll
  for (int tt = 0; tt < 8; ++tt)
    #pragma unroll
    for (int e = 0; e < 4; ++e) of[tt][e] = 0.f;
  float m_i[4], l_i[4];
  #pragma unroll
  for (int r = 0; r < 4; ++r) { m_i[r] = -1e30f; l_i[r] = 0.f; }

  const float scale = 0.08838834764831845f;   // 1/sqrt(128)

  for (int k0 = 0; k0 <= q0; k0 += 64) {
    __syncthreads();   // protect sK/sVt/sP from previous iteration's readers
    {
      // K tile [64][128]: coalesced 16B per thread
      int krow = t >> 4;            // 0..15
      int kcol = (t & 15) * 8;
      #pragma unroll
      for (int r = 0; r < 4; ++r)
        *(uint4*)&sK[r*16 + krow][kcol] =
            *(const uint4*)(qkv + (size_t)(k0 + r*16 + krow) * QKV_LD + K_OFF + kvh*HEADD + kcol);
      // V tile transposed into sVt[d][key]
      int vrow = t & 15;            // key within round
      int vcol = (t >> 4) * 8;      // d
      #pragma unroll
      for (int r = 0; r < 4; ++r) {
        uint4 v = *(const uint4*)(qkv + (size_t)(k0 + r*16 + vrow) * QKV_LD + V_OFF + kvh*HEADD + vcol);
        const unsigned short* pv = (const unsigned short*)&v;
        #pragma unroll
        for (int j = 0; j < 8; ++j)
          sVt[vcol + j][r*16 + vrow] = pv[j];
      }
    }
    __syncthreads();

    // S = Q K^T  (st[tn]: 16x16 tile, keys tn*16 + lrow)
    f32x4 st[4];
    #pragma unroll
    for (int tn = 0; tn < 4; ++tn)
      #pragma unroll
      for (int e = 0; e < 4; ++e) st[tn][e] = 0.f;
    #pragma unroll
    for (int ks = 0; ks < 4; ++ks)
      #pragma unroll
      for (int tn = 0; tn < 4; ++tn) {
        bf16x8 kb = *(const bf16x8*)&sK[tn*16 + lrow][ks*32 + kgrp*8];
        st[tn] = __builtin_amdgcn_mfma_f32_16x16x32_bf16(qf[ks], kb, st[tn], 0, 0, 0);
      }

    // scale + causal mask + block row-max
    float mrow[4];
    #pragma unroll
    for (int r = 0; r < 4; ++r) mrow[r] = -1e30f;
    const int qrow_base = q0 + wave*16 + kgrp*4;
    #pragma unroll
    for (int tn = 0; tn < 4; ++tn) {
      int kcol = k0 + tn*16 + lrow;
      #pragma unroll
      for (int r = 0; r < 4; ++r) {
        float s = st[tn][r] * scale;
        if (kcol > qrow_base + r) s = -1e30f;
        st[tn][r] = s;
        mrow[r] = fmaxf(mrow[r], s);
      }
    }
    #pragma unroll
    for (int r = 0; r < 4; ++r)
      #pragma unroll
      for (int off = 1; off < 16; off <<= 1)
        mrow[r] = fmaxf(mrow[r], __shfl_xor(mrow[r], off, 16));

    float alpha[4];
    #pragma unroll
    for (int r = 0; r < 4; ++r) {
      float mnew = fmaxf(m_i[r], mrow[r]);
      alpha[r] = __expf(m_i[r] - mnew);
      m_i[r] = mnew;
    }

    float rsum[4] = {0.f, 0.f, 0.f, 0.f};
    #pragma unroll
    for (int tn = 0; tn < 4; ++tn)
      #pragma unroll
      for (int r = 0; r < 4; ++r) {
        float pr = __expf(st[tn][r] - m_i[r]);
        rsum[r] += pr;
        sP[wave*16 + kgrp*4 + r][tn*16 + lrow] = f2bf(pr);
      }
    #pragma unroll
    for (int r = 0; r < 4; ++r) {
      #pragma unroll
      for (int off = 1; off < 16; off <<= 1)
        rsum[r] += __shfl_xor(rsum[r], off, 16);
      l_i[r] = l_i[r] * alpha[r] + rsum[r];
    }
    #pragma unroll
    for (int tt = 0; tt < 8; ++tt)
      #pragma unroll
      for (int r = 0; r < 4; ++r)
        of[tt][r] *= alpha[r];

    __syncthreads();   // sP visible

    // O += P V   (A = P from LDS, B = V^T tile: both contiguous b128 reads)
    #pragma unroll
    for (int ks = 0; ks < 2; ++ks) {
      bf16x8 pa = *(const bf16x8*)&sP[wave*16 + lrow][ks*32 + kgrp*8];
      #pragma unroll
      for (int tt = 0; tt < 8; ++tt) {
        bf16x8 vb = *(const bf16x8*)&sVt[tt*16 + lrow][ks*32 + kgrp*8];
        of[tt] = __builtin_amdgcn_mfma_f32_16x16x32_bf16(pa, vb, of[tt], 0, 0, 0);
      }
    }
  }

  // epilogue: normalize and write into the Q region (in-place)
  #pragma unroll
  for (int r = 0; r < 4; ++r) {
    int row = q0 + wave*16 + kgrp*4 + r;
    float inv = 1.f / l_i[r];
    #pragma unroll
    for (int tt = 0; tt < 8; ++tt)
      qkv[(size_t)row * QKV_LD + h*HEADD + tt*16 + lrow] = f2bf(of[tt][r] * inv);
  }
}

// ---------------------------------------------------------------------------
extern "C" void kernel_launch(void* const* d_in, const int* in_sizes, int n_in,
                              void* d_out, int out_size, void* d_ws, size_t ws_size,
                              hipStream_t stream) {
  const float* hs    = (const float*)d_in[0];   // f32 [2048][4096]
  const int*   pos   = (const int*)d_in[1];     // int32 [2048]
  const float* w_qkv = (const float*)d_in[2];   // f32 [6144][4096]
  const float* w_o   = (const float*)d_in[3];   // f32 [4096][4096]
  float*       out   = (float*)d_out;           // f32 [2048][4096]

  unsigned short* qkv = (unsigned short*)d_ws;  // bf16 [2048][6144] = 25.2 MB

  // 1) QKV projection (f32 A, f32 B -> bf16 C, ld 6144)
  gemm_bt<0, 0><<<dim3(SEQ/128, QKV_LD/128), 256, 0, stream>>>(
      hs, w_qkv, qkv, SEQ, QKV_LD, HDIM, HDIM, QKV_LD);
  // 2) RoPE on q,k (in-place, bf16)
  rope_kernel<<<(SEQ * 40 * 64) / 256, 256, 0, stream>>>(qkv, pos);
  // 3) causal GQA flash attention; output overwrites Q region of qkv
  attn_fwd<<<dim3(SEQ/64, NHEADS), 256, 0, stream>>>(qkv);
  // 4) output projection (bf16 A ld 6144, f32 B -> f32 C ld 4096)
  gemm_bt<1, 1><<<dim3(SEQ/128, HDIM/128), 256, 0, stream>>>(
      qkv, w_o, out, SEQ, HDIM, HDIM, QKV_LD, HDIM);
}

// Round 3
// 610.048 us; speedup vs baseline: 1.3548x; 1.3548x over previous
//
#include <hip/hip_runtime.h>

// Problem constants (B=1)
#define SEQ     2048
#define HDIM    4096
#define NHEADS  32
#define NKVH    8
#define HEADD   128
#define QKV_LD  6144      // NH*HD + 2*NKV*HD
#define K_OFF   4096      // q region size (elements)
#define V_OFF   5120      // q+k region size

typedef __bf16 bf16x8 __attribute__((ext_vector_type(8)));
typedef float  f32x4  __attribute__((ext_vector_type(4)));

__device__ inline float bf2f(unsigned short u) {
  return __uint_as_float(((unsigned int)u) << 16);
}
__device__ inline unsigned short f2bf(float f) {
  unsigned int u = __float_as_uint(f);
  u += 0x7fff + ((u >> 16) & 1);   // round-to-nearest-even
  return (unsigned short)(u >> 16);
}
__device__ inline unsigned int pack2bf(float a, float b) {
  return (unsigned int)f2bf(a) | ((unsigned int)f2bf(b) << 16);
}

// f32 -> bf16 bulk convert, 8 elements/thread/iter
__global__ __launch_bounds__(256) void cvt_bf16(
    const float* __restrict__ s, unsigned short* __restrict__ d, int n8) {
  int i = blockIdx.x * 256 + threadIdx.x;
  int stride = gridDim.x * 256;
  for (; i < n8; i += stride) {
    const float* p = s + (size_t)i * 8;
    float4 x = *(const float4*)p;
    float4 y = *(const float4*)(p + 4);
    uint4 pk;
    pk.x = pack2bf(x.x, x.y);
    pk.y = pack2bf(x.z, x.w);
    pk.z = pack2bf(y.x, y.y);
    pk.w = pack2bf(y.z, y.w);
    *(uint4*)(d + (size_t)i * 8) = pk;
  }
}

// ---------------------------------------------------------------------------
// C[m,n] = sum_k A[m,k] * B[n,k].  128x128 tile, BK=64, 4 waves in 2x2.
// bf16 operands staged via global_load_lds (16B) into an XOR-swizzled LDS
// tile: logical (row, colgroup cg of 8 bf16) lives at slot g = cg ^ (row&7).
// This makes the 16-row ds_read_b128 fragment reads 2-way (free) instead of
// 16-way bank-conflicted, while keeping the wave-uniform-base+lane*16 layout
// global_load_lds requires. f32 operands (fallback path) are packed in VALU.
// ---------------------------------------------------------------------------
template<int A_BF16, int B_BF16, int C_F32>
__global__ __launch_bounds__(256, 2) void gemm_bt(
    const void* __restrict__ Av,
    const void* __restrict__ Bv,
    void* __restrict__ Cv,
    int K, int lda, int ldb, int ldc) {
  __shared__ __align__(16) unsigned short sA[128][64];
  __shared__ __align__(16) unsigned short sB[128][64];

  const int t    = threadIdx.x;
  const int wave = t >> 6;
  const int lane = t & 63;
  const int lrow = lane & 15;   // m (A) / n (B) within 16-tile
  const int kgrp = lane >> 4;   // 0..3
  const int wm   = (wave >> 1) * 64;
  const int wn   = (wave & 1) * 64;
  const int m0   = blockIdx.x * 128;
  const int n0   = blockIdx.y * 128;

  f32x4 acc[4][4];
  #pragma unroll
  for (int i = 0; i < 4; ++i)
    #pragma unroll
    for (int j = 0; j < 4; ++j)
      #pragma unroll
      for (int e = 0; e < 4; ++e) acc[i][j][e] = 0.f;

  for (int k0 = 0; k0 < K; k0 += 64) {
    __syncthreads();
    // ---- A tile ----
    if constexpr (A_BF16) {
      #pragma unroll
      for (int c = 0; c < 4; ++c) {
        int chunk = wave * 4 + c;          // 8-row chunk, 1 KB
        int row   = chunk * 8 + (lane >> 3);
        int cg    = (lane & 7) ^ ((lane >> 3) & 7);   // logical col-group for this slot
        __builtin_amdgcn_global_load_lds(
            (const __attribute__((address_space(1))) unsigned int*)
                ((const unsigned short*)Av + (size_t)(m0 + row) * lda + k0 + cg * 8),
            (__attribute__((address_space(3))) unsigned int*)&sA[chunk * 8][0],
            16, 0, 0);
      }
    } else {
      #pragma unroll
      for (int r = 0; r < 4; ++r) {
        int row = r * 32 + (t >> 3);
        int cg  = t & 7;
        const float* p = (const float*)Av + (size_t)(m0 + row) * lda + k0 + cg * 8;
        float4 x = *(const float4*)p;
        float4 y = *(const float4*)(p + 4);
        uint4 pk;
        pk.x = pack2bf(x.x, x.y);
        pk.y = pack2bf(x.z, x.w);
        pk.z = pack2bf(y.x, y.y);
        pk.w = pack2bf(y.z, y.w);
        *(uint4*)&sA[row][(cg ^ (row & 7)) * 8] = pk;
      }
    }
    // ---- B tile ----
    if constexpr (B_BF16) {
      #pragma unroll
      for (int c = 0; c < 4; ++c) {
        int chunk = wave * 4 + c;
        int row   = chunk * 8 + (lane >> 3);
        int cg    = (lane & 7) ^ ((lane >> 3) & 7);
        __builtin_amdgcn_global_load_lds(
            (const __attribute__((address_space(1))) unsigned int*)
                ((const unsigned short*)Bv + (size_t)(n0 + row) * ldb + k0 + cg * 8),
            (__attribute__((address_space(3))) unsigned int*)&sB[chunk * 8][0],
            16, 0, 0);
      }
    } else {
      #pragma unroll
      for (int r = 0; r < 4; ++r) {
        int row = r * 32 + (t >> 3);
        int cg  = t & 7;
        const float* p = (const float*)Bv + (size_t)(n0 + row) * ldb + k0 + cg * 8;
        float4 x = *(const float4*)p;
        float4 y = *(const float4*)(p + 4);
        uint4 pk;
        pk.x = pack2bf(x.x, x.y);
        pk.y = pack2bf(x.z, x.w);
        pk.z = pack2bf(y.x, y.y);
        pk.w = pack2bf(y.z, y.w);
        *(uint4*)&sB[row][(cg ^ (row & 7)) * 8] = pk;
      }
    }
    __syncthreads();

    #pragma unroll
    for (int ks = 0; ks < 2; ++ks) {
      bf16x8 af[4], bfm[4];
      #pragma unroll
      for (int i = 0; i < 4; ++i)
        af[i] = *(const bf16x8*)&sA[wm + i*16 + lrow][((ks*4 + kgrp) ^ (lrow & 7)) * 8];
      #pragma unroll
      for (int j = 0; j < 4; ++j)
        bfm[j] = *(const bf16x8*)&sB[wn + j*16 + lrow][((ks*4 + kgrp) ^ (lrow & 7)) * 8];
      #pragma unroll
      for (int i = 0; i < 4; ++i)
        #pragma unroll
        for (int j = 0; j < 4; ++j)
          acc[i][j] = __builtin_amdgcn_mfma_f32_16x16x32_bf16(af[i], bfm[j], acc[i][j], 0, 0, 0);
    }
  }

  // epilogue: C/D layout col=lane&15, row=(lane>>4)*4+reg
  #pragma unroll
  for (int i = 0; i < 4; ++i) {
    #pragma unroll
    for (int r = 0; r < 4; ++r) {
      int row = m0 + wm + i*16 + kgrp*4 + r;
      #pragma unroll
      for (int j = 0; j < 4; ++j) {
        int col = n0 + wn + j*16 + lrow;
        if constexpr (C_F32)
          ((float*)Cv)[(size_t)row * ldc + col] = acc[i][j][r];
        else
          ((unsigned short*)Cv)[(size_t)row * ldc + col] = f2bf(acc[i][j][r]);
      }
    }
  }
}

// ---------------------------------------------------------------------------
// RoPE in-place on q (heads 0..31) and k (heads 32..39) of the bf16 qkv buffer.
// ---------------------------------------------------------------------------
__global__ __launch_bounds__(256) void rope_kernel(
    unsigned short* __restrict__ qkv, const int* __restrict__ pos) {
  int tid  = blockIdx.x * 256 + threadIdx.x;
  int d    = tid & 63;
  int rh   = tid >> 6;
  int head = rh % 40;          // 0..31 q, 32..39 k (regions contiguous)
  int s    = rh / 40;
  if (s >= SEQ) return;
  unsigned short* p = qkv + (size_t)s * QKV_LD + head * 128 + d;
  float x1 = bf2f(p[0]);
  float x2 = bf2f(p[64]);
  float inv = __expf((float)d * -0.17988946039016608f);  // 1e5^(-d/64)
  float ang = (float)pos[s] * inv;
  float sn, c;
  sincosf(ang, &sn, &c);
  p[0]  = f2bf(x1 * c - x2 * sn);
  p[64] = f2bf(x2 * c + x1 * sn);
}

// ---------------------------------------------------------------------------
// Causal flash attention with GQA. One block = (64 q-rows, 1 head), 4 waves.
// Output written in-place into the Q region of qkv.
// ---------------------------------------------------------------------------
__global__ __launch_bounds__(256, 2) void attn_fwd(
    unsigned short* __restrict__ qkv) {
  __shared__ __align__(16) unsigned short sK[64][136];    // [key][d], +8 pad
  __shared__ __align__(16) unsigned short sVt[128][72];   // [d][key] transposed
  __shared__ __align__(16) unsigned short sP[64][72];     // [q][key], +8 pad

  const int t    = threadIdx.x;
  const int wave = t >> 6;
  const int lane = t & 63;
  const int lrow = lane & 15;
  const int kgrp = lane >> 4;
  const int q0   = blockIdx.x * 64;
  const int h    = blockIdx.y;
  const int kvh  = h >> 2;                  // GROUPS = 4

  bf16x8 qf[4];
  {
    const unsigned short* qrow =
        qkv + (size_t)(q0 + wave*16 + lrow) * QKV_LD + h * HEADD;
    #pragma unroll
    for (int ks = 0; ks < 4; ++ks)
      qf[ks] = *(const bf16x8*)(qrow + ks*32 + kgrp*8);
  }

  f32x4 of[8];
  #pragma unroll
  for (int tt = 0; tt < 8; ++tt)
    #pragma unroll
    for (int e = 0; e < 4; ++e) of[tt][e] = 0.f;
  float m_i[4], l_i[4];
  #pragma unroll
  for (int r = 0; r < 4; ++r) { m_i[r] = -1e30f; l_i[r] = 0.f; }

  const float scale = 0.08838834764831845f;   // 1/sqrt(128)

  for (int k0 = 0; k0 <= q0; k0 += 64) {
    __syncthreads();
    {
      int krow = t >> 4;            // 0..15
      int kcol = (t & 15) * 8;
      #pragma unroll
      for (int r = 0; r < 4; ++r)
        *(uint4*)&sK[r*16 + krow][kcol] =
            *(const uint4*)(qkv + (size_t)(k0 + r*16 + krow) * QKV_LD + K_OFF + kvh*HEADD + kcol);
      int vrow = t & 15;
      int vcol = (t >> 4) * 8;
      #pragma unroll
      for (int r = 0; r < 4; ++r) {
        uint4 v = *(const uint4*)(qkv + (size_t)(k0 + r*16 + vrow) * QKV_LD + V_OFF + kvh*HEADD + vcol);
        const unsigned short* pv = (const unsigned short*)&v;
        #pragma unroll
        for (int j = 0; j < 8; ++j)
          sVt[vcol + j][r*16 + vrow] = pv[j];
      }
    }
    __syncthreads();

    f32x4 st[4];
    #pragma unroll
    for (int tn = 0; tn < 4; ++tn)
      #pragma unroll
      for (int e = 0; e < 4; ++e) st[tn][e] = 0.f;
    #pragma unroll
    for (int ks = 0; ks < 4; ++ks)
      #pragma unroll
      for (int tn = 0; tn < 4; ++tn) {
        bf16x8 kb = *(const bf16x8*)&sK[tn*16 + lrow][ks*32 + kgrp*8];
        st[tn] = __builtin_amdgcn_mfma_f32_16x16x32_bf16(qf[ks], kb, st[tn], 0, 0, 0);
      }

    float mrow[4];
    #pragma unroll
    for (int r = 0; r < 4; ++r) mrow[r] = -1e30f;
    const int qrow_base = q0 + wave*16 + kgrp*4;
    #pragma unroll
    for (int tn = 0; tn < 4; ++tn) {
      int kcol = k0 + tn*16 + lrow;
      #pragma unroll
      for (int r = 0; r < 4; ++r) {
        float s = st[tn][r] * scale;
        if (kcol > qrow_base + r) s = -1e30f;
        st[tn][r] = s;
        mrow[r] = fmaxf(mrow[r], s);
      }
    }
    #pragma unroll
    for (int r = 0; r < 4; ++r)
      #pragma unroll
      for (int off = 1; off < 16; off <<= 1)
        mrow[r] = fmaxf(mrow[r], __shfl_xor(mrow[r], off, 16));

    float alpha[4];
    #pragma unroll
    for (int r = 0; r < 4; ++r) {
      float mnew = fmaxf(m_i[r], mrow[r]);
      alpha[r] = __expf(m_i[r] - mnew);
      m_i[r] = mnew;
    }

    float rsum[4] = {0.f, 0.f, 0.f, 0.f};
    #pragma unroll
    for (int tn = 0; tn < 4; ++tn)
      #pragma unroll
      for (int r = 0; r < 4; ++r) {
        float pr = __expf(st[tn][r] - m_i[r]);
        rsum[r] += pr;
        sP[wave*16 + kgrp*4 + r][tn*16 + lrow] = f2bf(pr);
      }
    #pragma unroll
    for (int r = 0; r < 4; ++r) {
      #pragma unroll
      for (int off = 1; off < 16; off <<= 1)
        rsum[r] += __shfl_xor(rsum[r], off, 16);
      l_i[r] = l_i[r] * alpha[r] + rsum[r];
    }
    #pragma unroll
    for (int tt = 0; tt < 8; ++tt)
      #pragma unroll
      for (int r = 0; r < 4; ++r)
        of[tt][r] *= alpha[r];

    __syncthreads();

    #pragma unroll
    for (int ks = 0; ks < 2; ++ks) {
      bf16x8 pa = *(const bf16x8*)&sP[wave*16 + lrow][ks*32 + kgrp*8];
      #pragma unroll
      for (int tt = 0; tt < 8; ++tt) {
        bf16x8 vb = *(const bf16x8*)&sVt[tt*16 + lrow][ks*32 + kgrp*8];
        of[tt] = __builtin_amdgcn_mfma_f32_16x16x32_bf16(pa, vb, of[tt], 0, 0, 0);
      }
    }
  }

  #pragma unroll
  for (int r = 0; r < 4; ++r) {
    int row = q0 + wave*16 + kgrp*4 + r;
    float inv = 1.f / l_i[r];
    #pragma unroll
    for (int tt = 0; tt < 8; ++tt)
      qkv[(size_t)row * QKV_LD + h*HEADD + tt*16 + lrow] = f2bf(of[tt][r] * inv);
  }
}

// ---------------------------------------------------------------------------
extern "C" void kernel_launch(void* const* d_in, const int* in_sizes, int n_in,
                              void* d_out, int out_size, void* d_ws, size_t ws_size,
                              hipStream_t stream) {
  const float* hs    = (const float*)d_in[0];   // f32 [2048][4096]
  const int*   pos   = (const int*)d_in[1];     // int32 [2048]
  const float* w_qkv = (const float*)d_in[2];   // f32 [6144][4096]
  const float* w_o   = (const float*)d_in[3];   // f32 [4096][4096]
  float*       out   = (float*)d_out;           // f32 [2048][4096]

  const size_t N_QKV  = (size_t)SEQ * QKV_LD;     // 12.58M
  const size_t N_HS   = (size_t)SEQ * HDIM;       //  8.39M
  const size_t N_WQKV = (size_t)QKV_LD * HDIM;    // 25.17M
  const size_t N_WO   = (size_t)HDIM * HDIM;      // 16.78M

  unsigned short* qkv = (unsigned short*)d_ws;    // bf16 [2048][6144]

  const size_t full_ws = (N_QKV + N_HS + N_WQKV + N_WO) * 2;  // ~126 MB

  if (ws_size >= full_ws) {
    unsigned short* hs_b   = qkv + N_QKV;
    unsigned short* wqkv_b = hs_b + N_HS;
    unsigned short* wo_b   = wqkv_b + N_WQKV;

    cvt_bf16<<<2048, 256, 0, stream>>>(hs,    hs_b,   (int)(N_HS   / 8));
    cvt_bf16<<<2048, 256, 0, stream>>>(w_qkv, wqkv_b, (int)(N_WQKV / 8));
    cvt_bf16<<<2048, 256, 0, stream>>>(w_o,   wo_b,   (int)(N_WO   / 8));

    gemm_bt<1, 1, 0><<<dim3(SEQ/128, QKV_LD/128), 256, 0, stream>>>(
        hs_b, wqkv_b, qkv, HDIM, HDIM, HDIM, QKV_LD);
    rope_kernel<<<(SEQ * 40 * 64) / 256, 256, 0, stream>>>(qkv, pos);
    attn_fwd<<<dim3(SEQ/64, NHEADS), 256, 0, stream>>>(qkv);
    gemm_bt<1, 1, 1><<<dim3(SEQ/128, HDIM/128), 256, 0, stream>>>(
        qkv, wo_b, out, HDIM, QKV_LD, HDIM, HDIM);
  } else {
    // fallback: inline f32->bf16 packing during staging (round-2 path)
    gemm_bt<0, 0, 0><<<dim3(SEQ/128, QKV_LD/128), 256, 0, stream>>>(
        hs, w_qkv, qkv, HDIM, HDIM, HDIM, QKV_LD);
    rope_kernel<<<(SEQ * 40 * 64) / 256, 256, 0, stream>>>(qkv, pos);
    attn_fwd<<<dim3(SEQ/64, NHEADS), 256, 0, stream>>>(qkv);
    gemm_bt<1, 0, 1><<<dim3(SEQ/128, HDIM/128), 256, 0, stream>>>(
        qkv, w_o, out, HDIM, QKV_LD, HDIM, HDIM);
  }
}

// Round 4
// 537.148 us; speedup vs baseline: 1.5387x; 1.1357x over previous
//
#include <hip/hip_runtime.h>

// Problem constants (B=1)
#define SEQ     2048
#define HDIM    4096
#define NHEADS  32
#define NKVH    8
#define HEADD   128
#define QKV_LD  6144      // NH*HD + 2*NKV*HD
#define K_OFF   4096      // q region size (elements)
#define V_OFF   5120      // q+k region size

typedef __bf16 bf16x8 __attribute__((ext_vector_type(8)));
typedef float  f32x4  __attribute__((ext_vector_type(4)));

__device__ inline float bf2f(unsigned short u) {
  return __uint_as_float(((unsigned int)u) << 16);
}
__device__ inline unsigned short f2bf(float f) {
  unsigned int u = __float_as_uint(f);
  u += 0x7fff + ((u >> 16) & 1);   // round-to-nearest-even
  return (unsigned short)(u >> 16);
}
__device__ inline unsigned int pack2bf(float a, float b) {
  return (unsigned int)f2bf(a) | ((unsigned int)f2bf(b) << 16);
}

// f32 -> bf16 bulk convert, 8 elements/thread/iter
__global__ __launch_bounds__(256) void cvt_bf16(
    const float* __restrict__ s, unsigned short* __restrict__ d, int n8) {
  int i = blockIdx.x * 256 + threadIdx.x;
  int stride = gridDim.x * 256;
  for (; i < n8; i += stride) {
    const float* p = s + (size_t)i * 8;
    float4 x = *(const float4*)p;
    float4 y = *(const float4*)(p + 4);
    uint4 pk;
    pk.x = pack2bf(x.x, x.y);
    pk.y = pack2bf(x.z, x.w);
    pk.z = pack2bf(y.x, y.y);
    pk.w = pack2bf(y.z, y.w);
    *(uint4*)(d + (size_t)i * 8) = pk;
  }
}

// ---------------------------------------------------------------------------
// C[m,n] = sum_k A[m,k] * B[n,k].  128x128 tile, BK=64, 4 waves in 2x2.
// bf16 operands staged via global_load_lds (16B) into an XOR-swizzled LDS
// tile (slot = cg ^ (row&7)).
// ---------------------------------------------------------------------------
template<int A_BF16, int B_BF16, int C_F32>
__global__ __launch_bounds__(256, 2) void gemm_bt(
    const void* __restrict__ Av,
    const void* __restrict__ Bv,
    void* __restrict__ Cv,
    int K, int lda, int ldb, int ldc) {
  __shared__ __align__(16) unsigned short sA[128][64];
  __shared__ __align__(16) unsigned short sB[128][64];

  const int t    = threadIdx.x;
  const int wave = t >> 6;
  const int lane = t & 63;
  const int lrow = lane & 15;   // m (A) / n (B) within 16-tile
  const int kgrp = lane >> 4;   // 0..3
  const int wm   = (wave >> 1) * 64;
  const int wn   = (wave & 1) * 64;
  const int m0   = blockIdx.x * 128;
  const int n0   = blockIdx.y * 128;

  f32x4 acc[4][4];
  #pragma unroll
  for (int i = 0; i < 4; ++i)
    #pragma unroll
    for (int j = 0; j < 4; ++j)
      #pragma unroll
      for (int e = 0; e < 4; ++e) acc[i][j][e] = 0.f;

  for (int k0 = 0; k0 < K; k0 += 64) {
    __syncthreads();
    // ---- A tile ----
    if constexpr (A_BF16) {
      #pragma unroll
      for (int c = 0; c < 4; ++c) {
        int chunk = wave * 4 + c;          // 8-row chunk, 1 KB
        int row   = chunk * 8 + (lane >> 3);
        int cg    = (lane & 7) ^ ((lane >> 3) & 7);
        __builtin_amdgcn_global_load_lds(
            (const __attribute__((address_space(1))) unsigned int*)
                ((const unsigned short*)Av + (size_t)(m0 + row) * lda + k0 + cg * 8),
            (__attribute__((address_space(3))) unsigned int*)&sA[chunk * 8][0],
            16, 0, 0);
      }
    } else {
      #pragma unroll
      for (int r = 0; r < 4; ++r) {
        int row = r * 32 + (t >> 3);
        int cg  = t & 7;
        const float* p = (const float*)Av + (size_t)(m0 + row) * lda + k0 + cg * 8;
        float4 x = *(const float4*)p;
        float4 y = *(const float4*)(p + 4);
        uint4 pk;
        pk.x = pack2bf(x.x, x.y);
        pk.y = pack2bf(x.z, x.w);
        pk.z = pack2bf(y.x, y.y);
        pk.w = pack2bf(y.z, y.w);
        *(uint4*)&sA[row][(cg ^ (row & 7)) * 8] = pk;
      }
    }
    // ---- B tile ----
    if constexpr (B_BF16) {
      #pragma unroll
      for (int c = 0; c < 4; ++c) {
        int chunk = wave * 4 + c;
        int row   = chunk * 8 + (lane >> 3);
        int cg    = (lane & 7) ^ ((lane >> 3) & 7);
        __builtin_amdgcn_global_load_lds(
            (const __attribute__((address_space(1))) unsigned int*)
                ((const unsigned short*)Bv + (size_t)(n0 + row) * ldb + k0 + cg * 8),
            (__attribute__((address_space(3))) unsigned int*)&sB[chunk * 8][0],
            16, 0, 0);
      }
    } else {
      #pragma unroll
      for (int r = 0; r < 4; ++r) {
        int row = r * 32 + (t >> 3);
        int cg  = t & 7;
        const float* p = (const float*)Bv + (size_t)(n0 + row) * ldb + k0 + cg * 8;
        float4 x = *(const float4*)p;
        float4 y = *(const float4*)(p + 4);
        uint4 pk;
        pk.x = pack2bf(x.x, x.y);
        pk.y = pack2bf(x.z, x.w);
        pk.z = pack2bf(y.x, y.y);
        pk.w = pack2bf(y.z, y.w);
        *(uint4*)&sB[row][(cg ^ (row & 7)) * 8] = pk;
      }
    }
    __syncthreads();

    #pragma unroll
    for (int ks = 0; ks < 2; ++ks) {
      bf16x8 af[4], bfm[4];
      #pragma unroll
      for (int i = 0; i < 4; ++i)
        af[i] = *(const bf16x8*)&sA[wm + i*16 + lrow][((ks*4 + kgrp) ^ (lrow & 7)) * 8];
      #pragma unroll
      for (int j = 0; j < 4; ++j)
        bfm[j] = *(const bf16x8*)&sB[wn + j*16 + lrow][((ks*4 + kgrp) ^ (lrow & 7)) * 8];
      #pragma unroll
      for (int i = 0; i < 4; ++i)
        #pragma unroll
        for (int j = 0; j < 4; ++j)
          acc[i][j] = __builtin_amdgcn_mfma_f32_16x16x32_bf16(af[i], bfm[j], acc[i][j], 0, 0, 0);
    }
  }

  // epilogue: C/D layout col=lane&15, row=(lane>>4)*4+reg
  #pragma unroll
  for (int i = 0; i < 4; ++i) {
    #pragma unroll
    for (int r = 0; r < 4; ++r) {
      int row = m0 + wm + i*16 + kgrp*4 + r;
      #pragma unroll
      for (int j = 0; j < 4; ++j) {
        int col = n0 + wn + j*16 + lrow;
        if constexpr (C_F32)
          ((float*)Cv)[(size_t)row * ldc + col] = acc[i][j][r];
        else
          ((unsigned short*)Cv)[(size_t)row * ldc + col] = f2bf(acc[i][j][r]);
      }
    }
  }
}

// ---------------------------------------------------------------------------
// RoPE in-place on q (heads 0..31) and k (heads 32..39) of the bf16 qkv buffer.
// ---------------------------------------------------------------------------
__global__ __launch_bounds__(256) void rope_kernel(
    unsigned short* __restrict__ qkv, const int* __restrict__ pos) {
  int tid  = blockIdx.x * 256 + threadIdx.x;
  int d    = tid & 63;
  int rh   = tid >> 6;
  int head = rh % 40;          // 0..31 q, 32..39 k
  int s    = rh / 40;
  if (s >= SEQ) return;
  unsigned short* p = qkv + (size_t)s * QKV_LD + head * 128 + d;
  float x1 = bf2f(p[0]);
  float x2 = bf2f(p[64]);
  float inv = __expf((float)d * -0.17988946039016608f);  // 1e5^(-d/64)
  float ang = (float)pos[s] * inv;
  float sn, c;
  sincosf(ang, &sn, &c);
  p[0]  = f2bf(x1 * c - x2 * sn);
  p[64] = f2bf(x2 * c + x1 * sn);
}

// ---------------------------------------------------------------------------
// Transpose the V region: qkv[s][V_OFF + c] -> vT[c][s]   (c = kvh*128 + d)
// ---------------------------------------------------------------------------
__global__ __launch_bounds__(256) void transpose_v(
    const unsigned short* __restrict__ qkv, unsigned short* __restrict__ vT) {
  __shared__ unsigned short tile[64][72];   // +8 pad
  const int t  = threadIdx.x;
  const int s0 = blockIdx.x * 64;
  const int c0 = blockIdx.y * 64;
  const int r  = t >> 3;          // 0..31
  const int cg = (t & 7) * 8;
  #pragma unroll
  for (int rr = 0; rr < 2; ++rr) {
    int row = rr * 32 + r;
    *(uint4*)&tile[row][cg] =
        *(const uint4*)(qkv + (size_t)(s0 + row) * QKV_LD + V_OFF + c0 + cg);
  }
  __syncthreads();
  #pragma unroll
  for (int rr = 0; rr < 2; ++rr) {
    int c = rr * 32 + r;
    unsigned short v[8];
    #pragma unroll
    for (int j = 0; j < 8; ++j) v[j] = tile[cg + j][c];
    *(uint4*)(vT + (size_t)(c0 + c) * SEQ + s0 + cg) = *(uint4*)v;
  }
}

// ---------------------------------------------------------------------------
// Attention helpers (dual-Q-tile balanced kernel)
// ---------------------------------------------------------------------------
__device__ __forceinline__ void qk_softmax_tile(
    const bf16x8* qf, const unsigned short (*sK)[128],
    unsigned short (*sP)[72],
    f32x4* of, float* m_i, float* l_i,
    int lane, int wave, int dq) {
  const int lrow = lane & 15;
  const int kgrp = lane >> 4;
  f32x4 st[4];
  #pragma unroll
  for (int tn = 0; tn < 4; ++tn)
    #pragma unroll
    for (int e = 0; e < 4; ++e) st[tn][e] = 0.f;
  #pragma unroll
  for (int ks = 0; ks < 4; ++ks) {
    #pragma unroll
    for (int tn = 0; tn < 4; ++tn) {
      int cgr = ks * 4 + kgrp;
      const bf16x8 kb = *(const bf16x8*)
          &sK[tn*16 + lrow][((cgr & 8) | ((cgr & 7) ^ (lrow & 7))) * 8];
      st[tn] = __builtin_amdgcn_mfma_f32_16x16x32_bf16(qf[ks], kb, st[tn], 0, 0, 0);
    }
  }
  const float scale2 = 0.12751743f;   // log2(e)/sqrt(128)
  float mrow[4] = {-1e30f, -1e30f, -1e30f, -1e30f};
  #pragma unroll
  for (int tn = 0; tn < 4; ++tn) {
    #pragma unroll
    for (int r = 0; r < 4; ++r) {
      float s = st[tn][r] * scale2;
      if (tn*16 + lrow > dq + r) s = -1e30f;   // inert off-diagonal (dq >= 64)
      st[tn][r] = s;
      mrow[r] = fmaxf(mrow[r], s);
    }
  }
  #pragma unroll
  for (int r = 0; r < 4; ++r)
    #pragma unroll
    for (int off = 1; off < 16; off <<= 1)
      mrow[r] = fmaxf(mrow[r], __shfl_xor(mrow[r], off, 16));
  float alpha[4];
  #pragma unroll
  for (int r = 0; r < 4; ++r) {
    float mnew = fmaxf(m_i[r], mrow[r]);
    alpha[r] = exp2f(m_i[r] - mnew);
    m_i[r] = mnew;
  }
  float rsum[4] = {0.f, 0.f, 0.f, 0.f};
  #pragma unroll
  for (int tn = 0; tn < 4; ++tn)
    #pragma unroll
    for (int r = 0; r < 4; ++r) {
      float pr = exp2f(st[tn][r] - m_i[r]);
      rsum[r] += pr;
      sP[wave*16 + kgrp*4 + r][tn*16 + lrow] = f2bf(pr);
    }
  #pragma unroll
  for (int r = 0; r < 4; ++r) {
    #pragma unroll
    for (int off = 1; off < 16; off <<= 1)
      rsum[r] += __shfl_xor(rsum[r], off, 16);
    l_i[r] = l_i[r] * alpha[r] + rsum[r];
  }
  #pragma unroll
  for (int tt = 0; tt < 8; ++tt)
    #pragma unroll
    for (int r = 0; r < 4; ++r)
      of[tt][r] *= alpha[r];
}

__device__ __forceinline__ void pv_tile(
    const unsigned short (*sP)[72], const unsigned short (*sVt)[64],
    f32x4* of, int lane, int wave) {
  const int lrow = lane & 15;
  const int kgrp = lane >> 4;
  #pragma unroll
  for (int ks = 0; ks < 2; ++ks) {
    const bf16x8 pa = *(const bf16x8*)&sP[wave*16 + lrow][ks*32 + kgrp*8];
    #pragma unroll
    for (int tt = 0; tt < 8; ++tt) {
      int cgr = ks * 4 + kgrp;
      const bf16x8 vb = *(const bf16x8*)
          &sVt[tt*16 + lrow][(cgr ^ (lrow & 7)) * 8];
      of[tt] = __builtin_amdgcn_mfma_f32_16x16x32_bf16(pa, vb, of[tt], 0, 0, 0);
    }
  }
}

// ---------------------------------------------------------------------------
// Balanced causal flash attention, GQA. Block p of 16 handles Q-tiles
// p (low) and 31-p (high), 64 rows each; KV staged ONCE per key-tile and
// shared between both while both are active. All blocks: 33 MFMA tile-iters.
// K and V^T staged via global_load_lds with XOR swizzle. O written in-place
// into the Q region of qkv.
// ---------------------------------------------------------------------------
__global__ __launch_bounds__(256, 2) void attn_fwd2(
    unsigned short* __restrict__ qkv, const unsigned short* __restrict__ vT) {
  __shared__ __align__(16) unsigned short sK[64][128];   // [key][d] swizzled
  __shared__ __align__(16) unsigned short sVt[128][64];  // [d][key] swizzled
  __shared__ __align__(16) unsigned short sP[128][72];   // rows 0-63 hi, 64-127 lo

  const int t    = threadIdx.x;
  const int wave = t >> 6;
  const int lane = t & 63;
  const int lrow = lane & 15;
  const int kgrp = lane >> 4;
  const int p    = blockIdx.x;          // 0..15
  const int h    = blockIdx.y;
  const int kvh  = h >> 2;
  const int qLo  = p * 64;
  const int qHi  = (31 - p) * 64;
  const int nTiles = 32 - p;            // key-tiles for high Q-tile
  const int nDual  = p + 1;             // key-tiles where low tile is active

  bf16x8 qfH[4], qfL[4];
  {
    const unsigned short* qr =
        qkv + (size_t)(qHi + wave*16 + lrow) * QKV_LD + h * HEADD;
    #pragma unroll
    for (int ks = 0; ks < 4; ++ks) qfH[ks] = *(const bf16x8*)(qr + ks*32 + kgrp*8);
    qr = qkv + (size_t)(qLo + wave*16 + lrow) * QKV_LD + h * HEADD;
    #pragma unroll
    for (int ks = 0; ks < 4; ++ks) qfL[ks] = *(const bf16x8*)(qr + ks*32 + kgrp*8);
  }

  f32x4 ofH[8], ofL[8];
  float mH[4], lH[4], mL[4], lL[4];
  #pragma unroll
  for (int tt = 0; tt < 8; ++tt)
    #pragma unroll
    for (int e = 0; e < 4; ++e) { ofH[tt][e] = 0.f; ofL[tt][e] = 0.f; }
  #pragma unroll
  for (int r = 0; r < 4; ++r) { mH[r] = -1e30f; lH[r] = 0.f; mL[r] = -1e30f; lL[r] = 0.f; }

  for (int kt = 0; kt < nTiles; ++kt) {
    const int k0 = kt * 64;
    __syncthreads();
    // stage K tile (64x128): 16 chunks of 4 rows (1 KB each)
    #pragma unroll
    for (int c = 0; c < 4; ++c) {
      int cc   = wave * 4 + c;
      int grow = cc * 4 + (lane >> 4);
      int slot = lane & 15;
      int cg   = (slot & 8) | ((slot & 7) ^ (grow & 7));
      __builtin_amdgcn_global_load_lds(
          (const __attribute__((address_space(1))) unsigned int*)
              (qkv + (size_t)(k0 + grow) * QKV_LD + K_OFF + kvh*HEADD + cg*8),
          (__attribute__((address_space(3))) unsigned int*)&sK[cc*4][0],
          16, 0, 0);
    }
    // stage V^T tile (128x64): 16 chunks of 8 rows
    #pragma unroll
    for (int c = 0; c < 4; ++c) {
      int cc   = wave * 4 + c;
      int grow = cc * 8 + (lane >> 3);
      int slot = lane & 7;
      int cg   = slot ^ (grow & 7);
      __builtin_amdgcn_global_load_lds(
          (const __attribute__((address_space(1))) unsigned int*)
              (vT + (size_t)(kvh*HEADD + grow) * SEQ + k0 + cg*8),
          (__attribute__((address_space(3))) unsigned int*)&sVt[cc*8][0],
          16, 0, 0);
    }
    __syncthreads();

    const bool dual = (kt < nDual);
    qk_softmax_tile(qfH, sK, &sP[0],  ofH, mH, lH, lane, wave,
                    qHi + wave*16 + kgrp*4 - k0);
    if (dual)
      qk_softmax_tile(qfL, sK, &sP[64], ofL, mL, lL, lane, wave,
                      qLo + wave*16 + kgrp*4 - k0);
    __syncthreads();
    pv_tile(&sP[0], sVt, ofH, lane, wave);
    if (dual) pv_tile(&sP[64], sVt, ofL, lane, wave);
  }

  // epilogue: normalize, write both tiles in-place into the Q region
  #pragma unroll
  for (int r = 0; r < 4; ++r) {
    float invH = 1.f / lH[r];
    float invL = 1.f / lL[r];
    int rowH = qHi + wave*16 + kgrp*4 + r;
    int rowL = qLo + wave*16 + kgrp*4 + r;
    #pragma unroll
    for (int tt = 0; tt < 8; ++tt) {
      qkv[(size_t)rowH * QKV_LD + h*HEADD + tt*16 + lrow] = f2bf(ofH[tt][r] * invH);
      qkv[(size_t)rowL * QKV_LD + h*HEADD + tt*16 + lrow] = f2bf(ofL[tt][r] * invL);
    }
  }
}

// ---------------------------------------------------------------------------
// Fallback attention (round-2/3 path; no vT needed)
// ---------------------------------------------------------------------------
__global__ __launch_bounds__(256, 2) void attn_fwd(
    unsigned short* __restrict__ qkv) {
  __shared__ __align__(16) unsigned short sK[64][136];
  __shared__ __align__(16) unsigned short sVt[128][72];
  __shared__ __align__(16) unsigned short sP[64][72];

  const int t    = threadIdx.x;
  const int wave = t >> 6;
  const int lane = t & 63;
  const int lrow = lane & 15;
  const int kgrp = lane >> 4;
  const int q0   = blockIdx.x * 64;
  const int h    = blockIdx.y;
  const int kvh  = h >> 2;

  bf16x8 qf[4];
  {
    const unsigned short* qrow =
        qkv + (size_t)(q0 + wave*16 + lrow) * QKV_LD + h * HEADD;
    #pragma unroll
    for (int ks = 0; ks < 4; ++ks)
      qf[ks] = *(const bf16x8*)(qrow + ks*32 + kgrp*8);
  }

  f32x4 of[8];
  #pragma unroll
  for (int tt = 0; tt < 8; ++tt)
    #pragma unroll
    for (int e = 0; e < 4; ++e) of[tt][e] = 0.f;
  float m_i[4], l_i[4];
  #pragma unroll
  for (int r = 0; r < 4; ++r) { m_i[r] = -1e30f; l_i[r] = 0.f; }

  const float scale = 0.08838834764831845f;

  for (int k0 = 0; k0 <= q0; k0 += 64) {
    __syncthreads();
    {
      int krow = t >> 4;
      int kcol = (t & 15) * 8;
      #pragma unroll
      for (int r = 0; r < 4; ++r)
        *(uint4*)&sK[r*16 + krow][kcol] =
            *(const uint4*)(qkv + (size_t)(k0 + r*16 + krow) * QKV_LD + K_OFF + kvh*HEADD + kcol);
      int vrow = t & 15;
      int vcol = (t >> 4) * 8;
      #pragma unroll
      for (int r = 0; r < 4; ++r) {
        uint4 v = *(const uint4*)(qkv + (size_t)(k0 + r*16 + vrow) * QKV_LD + V_OFF + kvh*HEADD + vcol);
        const unsigned short* pv = (const unsigned short*)&v;
        #pragma unroll
        for (int j = 0; j < 8; ++j)
          sVt[vcol + j][r*16 + vrow] = pv[j];
      }
    }
    __syncthreads();

    f32x4 st[4];
    #pragma unroll
    for (int tn = 0; tn < 4; ++tn)
      #pragma unroll
      for (int e = 0; e < 4; ++e) st[tn][e] = 0.f;
    #pragma unroll
    for (int ks = 0; ks < 4; ++ks)
      #pragma unroll
      for (int tn = 0; tn < 4; ++tn) {
        bf16x8 kb = *(const bf16x8*)&sK[tn*16 + lrow][ks*32 + kgrp*8];
        st[tn] = __builtin_amdgcn_mfma_f32_16x16x32_bf16(qf[ks], kb, st[tn], 0, 0, 0);
      }

    float mrow[4];
    #pragma unroll
    for (int r = 0; r < 4; ++r) mrow[r] = -1e30f;
    const int qrow_base = q0 + wave*16 + kgrp*4;
    #pragma unroll
    for (int tn = 0; tn < 4; ++tn) {
      int kcol = k0 + tn*16 + lrow;
      #pragma unroll
      for (int r = 0; r < 4; ++r) {
        float s = st[tn][r] * scale;
        if (kcol > qrow_base + r) s = -1e30f;
        st[tn][r] = s;
        mrow[r] = fmaxf(mrow[r], s);
      }
    }
    #pragma unroll
    for (int r = 0; r < 4; ++r)
      #pragma unroll
      for (int off = 1; off < 16; off <<= 1)
        mrow[r] = fmaxf(mrow[r], __shfl_xor(mrow[r], off, 16));

    float alpha[4];
    #pragma unroll
    for (int r = 0; r < 4; ++r) {
      float mnew = fmaxf(m_i[r], mrow[r]);
      alpha[r] = __expf(m_i[r] - mnew);
      m_i[r] = mnew;
    }

    float rsum[4] = {0.f, 0.f, 0.f, 0.f};
    #pragma unroll
    for (int tn = 0; tn < 4; ++tn)
      #pragma unroll
      for (int r = 0; r < 4; ++r) {
        float pr = __expf(st[tn][r] - m_i[r]);
        rsum[r] += pr;
        sP[wave*16 + kgrp*4 + r][tn*16 + lrow] = f2bf(pr);
      }
    #pragma unroll
    for (int r = 0; r < 4; ++r) {
      #pragma unroll
      for (int off = 1; off < 16; off <<= 1)
        rsum[r] += __shfl_xor(rsum[r], off, 16);
      l_i[r] = l_i[r] * alpha[r] + rsum[r];
    }
    #pragma unroll
    for (int tt = 0; tt < 8; ++tt)
      #pragma unroll
      for (int r = 0; r < 4; ++r)
        of[tt][r] *= alpha[r];

    __syncthreads();

    #pragma unroll
    for (int ks = 0; ks < 2; ++ks) {
      bf16x8 pa = *(const bf16x8*)&sP[wave*16 + lrow][ks*32 + kgrp*8];
      #pragma unroll
      for (int tt = 0; tt < 8; ++tt) {
        bf16x8 vb = *(const bf16x8*)&sVt[tt*16 + lrow][ks*32 + kgrp*8];
        of[tt] = __builtin_amdgcn_mfma_f32_16x16x32_bf16(pa, vb, of[tt], 0, 0, 0);
      }
    }
  }

  #pragma unroll
  for (int r = 0; r < 4; ++r) {
    int row = q0 + wave*16 + kgrp*4 + r;
    float inv = 1.f / l_i[r];
    #pragma unroll
    for (int tt = 0; tt < 8; ++tt)
      qkv[(size_t)row * QKV_LD + h*HEADD + tt*16 + lrow] = f2bf(of[tt][r] * inv);
  }
}

// ---------------------------------------------------------------------------
extern "C" void kernel_launch(void* const* d_in, const int* in_sizes, int n_in,
                              void* d_out, int out_size, void* d_ws, size_t ws_size,
                              hipStream_t stream) {
  const float* hs    = (const float*)d_in[0];   // f32 [2048][4096]
  const int*   pos   = (const int*)d_in[1];     // int32 [2048]
  const float* w_qkv = (const float*)d_in[2];   // f32 [6144][4096]
  const float* w_o   = (const float*)d_in[3];   // f32 [4096][4096]
  float*       out   = (float*)d_out;           // f32 [2048][4096]

  const size_t N_QKV  = (size_t)SEQ * QKV_LD;
  const size_t N_HS   = (size_t)SEQ * HDIM;
  const size_t N_WQKV = (size_t)QKV_LD * HDIM;
  const size_t N_WO   = (size_t)HDIM * HDIM;

  unsigned short* qkv = (unsigned short*)d_ws;  // bf16 [2048][6144]

  const size_t full_ws = (N_QKV + N_HS + N_WQKV + N_WO) * 2;  // ~126 MB

  if (ws_size >= full_ws) {
    unsigned short* hs_b   = qkv + N_QKV;
    unsigned short* wqkv_b = hs_b + N_HS;
    unsigned short* wo_b   = wqkv_b + N_WQKV;
    // vT reuses hs_b (dead after the QKV GEMM): needs 1024*2048 <= N_HS elems
    unsigned short* vT     = hs_b;

    cvt_bf16<<<2048, 256, 0, stream>>>(hs,    hs_b,   (int)(N_HS   / 8));
    cvt_bf16<<<2048, 256, 0, stream>>>(w_qkv, wqkv_b, (int)(N_WQKV / 8));
    cvt_bf16<<<2048, 256, 0, stream>>>(w_o,   wo_b,   (int)(N_WO   / 8));

    gemm_bt<1, 1, 0><<<dim3(SEQ/128, QKV_LD/128), 256, 0, stream>>>(
        hs_b, wqkv_b, qkv, HDIM, HDIM, HDIM, QKV_LD);
    rope_kernel<<<(SEQ * 40 * 64) / 256, 256, 0, stream>>>(qkv, pos);
    transpose_v<<<dim3(SEQ/64, (NKVH*HEADD)/64), 256, 0, stream>>>(qkv, vT);
    attn_fwd2<<<dim3(16, NHEADS), 256, 0, stream>>>(qkv, vT);
    gemm_bt<1, 1, 1><<<dim3(SEQ/128, HDIM/128), 256, 0, stream>>>(
        qkv, wo_b, out, HDIM, QKV_LD, HDIM, HDIM);
  } else {
    // fallback: inline f32->bf16 packing during staging
    gemm_bt<0, 0, 0><<<dim3(SEQ/128, QKV_LD/128), 256, 0, stream>>>(
        hs, w_qkv, qkv, HDIM, HDIM, HDIM, QKV_LD);
    rope_kernel<<<(SEQ * 40 * 64) / 256, 256, 0, stream>>>(qkv, pos);
    attn_fwd<<<dim3(SEQ/64, NHEADS), 256, 0, stream>>>(qkv);
    gemm_bt<1, 0, 1><<<dim3(SEQ/128, HDIM/128), 256, 0, stream>>>(
        qkv, w_o, out, HDIM, QKV_LD, HDIM, HDIM);
  }
}

// Round 5
// 529.182 us; speedup vs baseline: 1.5619x; 1.0151x over previous
//
#include <hip/hip_runtime.h>

// Problem constants (B=1)
#define SEQ     2048
#define HDIM    4096
#define NHEADS  32
#define NKVH    8
#define HEADD   128
#define QKV_LD  6144      // NH*HD + 2*NKV*HD
#define K_OFF   4096      // q region size (elements)
#define V_OFF   5120      // q+k region size

typedef __bf16 bf16x8 __attribute__((ext_vector_type(8)));
typedef float  f32x4  __attribute__((ext_vector_type(4)));

__device__ inline float bf2f(unsigned short u) {
  return __uint_as_float(((unsigned int)u) << 16);
}
__device__ inline unsigned short f2bf(float f) {
  unsigned int u = __float_as_uint(f);
  u += 0x7fff + ((u >> 16) & 1);   // round-to-nearest-even
  return (unsigned short)(u >> 16);
}
__device__ inline unsigned int pack2bf(float a, float b) {
  return (unsigned int)f2bf(a) | ((unsigned int)f2bf(b) << 16);
}

// ---------------------------------------------------------------------------
// Fused f32 -> bf16 bulk convert of all three tensors (one launch).
// Destination regions are contiguous: [n0_8 | n1_8 | n2_8] (8-elem units).
// ---------------------------------------------------------------------------
__global__ __launch_bounds__(256) void cvt_all(
    const float* __restrict__ s0, const float* __restrict__ s1,
    const float* __restrict__ s2, unsigned short* __restrict__ d,
    int n0_8, int n1_8, int n2_8) {
  const int total = n0_8 + n1_8 + n2_8;
  for (int i = blockIdx.x * 256 + threadIdx.x; i < total; i += gridDim.x * 256) {
    const float* s; int off;
    if (i < n0_8)              { s = s0; off = i; }
    else if (i < n0_8 + n1_8)  { s = s1; off = i - n0_8; }
    else                       { s = s2; off = i - n0_8 - n1_8; }
    const float* p = s + (size_t)off * 8;
    float4 x = *(const float4*)p;
    float4 y = *(const float4*)(p + 4);
    uint4 pk;
    pk.x = pack2bf(x.x, x.y);
    pk.y = pack2bf(x.z, x.w);
    pk.z = pack2bf(y.x, y.y);
    pk.w = pack2bf(y.z, y.w);
    *(uint4*)(d + (size_t)i * 8) = pk;
  }
}

// ---------------------------------------------------------------------------
// C[m,n] = sum_k A[m,k] * B[n,k].  128x128 tile, BK=64, 4 waves in 2x2.
// bf16 operands staged via global_load_lds (16B) into an XOR-swizzled LDS
// tile (slot = cg ^ (row&7)).
// ---------------------------------------------------------------------------
template<int A_BF16, int B_BF16, int C_F32>
__global__ __launch_bounds__(256, 2) void gemm_bt(
    const void* __restrict__ Av,
    const void* __restrict__ Bv,
    void* __restrict__ Cv,
    int K, int lda, int ldb, int ldc) {
  __shared__ __align__(16) unsigned short sA[128][64];
  __shared__ __align__(16) unsigned short sB[128][64];

  const int t    = threadIdx.x;
  const int wave = t >> 6;
  const int lane = t & 63;
  const int lrow = lane & 15;   // m (A) / n (B) within 16-tile
  const int kgrp = lane >> 4;   // 0..3
  const int wm   = (wave >> 1) * 64;
  const int wn   = (wave & 1) * 64;
  const int m0   = blockIdx.x * 128;
  const int n0   = blockIdx.y * 128;

  f32x4 acc[4][4];
  #pragma unroll
  for (int i = 0; i < 4; ++i)
    #pragma unroll
    for (int j = 0; j < 4; ++j)
      #pragma unroll
      for (int e = 0; e < 4; ++e) acc[i][j][e] = 0.f;

  for (int k0 = 0; k0 < K; k0 += 64) {
    __syncthreads();
    // ---- A tile ----
    if constexpr (A_BF16) {
      #pragma unroll
      for (int c = 0; c < 4; ++c) {
        int chunk = wave * 4 + c;          // 8-row chunk, 1 KB
        int row   = chunk * 8 + (lane >> 3);
        int cg    = (lane & 7) ^ ((lane >> 3) & 7);
        __builtin_amdgcn_global_load_lds(
            (const __attribute__((address_space(1))) unsigned int*)
                ((const unsigned short*)Av + (size_t)(m0 + row) * lda + k0 + cg * 8),
            (__attribute__((address_space(3))) unsigned int*)&sA[chunk * 8][0],
            16, 0, 0);
      }
    } else {
      #pragma unroll
      for (int r = 0; r < 4; ++r) {
        int row = r * 32 + (t >> 3);
        int cg  = t & 7;
        const float* p = (const float*)Av + (size_t)(m0 + row) * lda + k0 + cg * 8;
        float4 x = *(const float4*)p;
        float4 y = *(const float4*)(p + 4);
        uint4 pk;
        pk.x = pack2bf(x.x, x.y);
        pk.y = pack2bf(x.z, x.w);
        pk.z = pack2bf(y.x, y.y);
        pk.w = pack2bf(y.z, y.w);
        *(uint4*)&sA[row][(cg ^ (row & 7)) * 8] = pk;
      }
    }
    // ---- B tile ----
    if constexpr (B_BF16) {
      #pragma unroll
      for (int c = 0; c < 4; ++c) {
        int chunk = wave * 4 + c;
        int row   = chunk * 8 + (lane >> 3);
        int cg    = (lane & 7) ^ ((lane >> 3) & 7);
        __builtin_amdgcn_global_load_lds(
            (const __attribute__((address_space(1))) unsigned int*)
                ((const unsigned short*)Bv + (size_t)(n0 + row) * ldb + k0 + cg * 8),
            (__attribute__((address_space(3))) unsigned int*)&sB[chunk * 8][0],
            16, 0, 0);
      }
    } else {
      #pragma unroll
      for (int r = 0; r < 4; ++r) {
        int row = r * 32 + (t >> 3);
        int cg  = t & 7;
        const float* p = (const float*)Bv + (size_t)(n0 + row) * ldb + k0 + cg * 8;
        float4 x = *(const float4*)p;
        float4 y = *(const float4*)(p + 4);
        uint4 pk;
        pk.x = pack2bf(x.x, x.y);
        pk.y = pack2bf(x.z, x.w);
        pk.z = pack2bf(y.x, y.y);
        pk.w = pack2bf(y.z, y.w);
        *(uint4*)&sB[row][(cg ^ (row & 7)) * 8] = pk;
      }
    }
    __syncthreads();

    #pragma unroll
    for (int ks = 0; ks < 2; ++ks) {
      bf16x8 af[4], bfm[4];
      #pragma unroll
      for (int i = 0; i < 4; ++i)
        af[i] = *(const bf16x8*)&sA[wm + i*16 + lrow][((ks*4 + kgrp) ^ (lrow & 7)) * 8];
      #pragma unroll
      for (int j = 0; j < 4; ++j)
        bfm[j] = *(const bf16x8*)&sB[wn + j*16 + lrow][((ks*4 + kgrp) ^ (lrow & 7)) * 8];
      #pragma unroll
      for (int i = 0; i < 4; ++i)
        #pragma unroll
        for (int j = 0; j < 4; ++j)
          acc[i][j] = __builtin_amdgcn_mfma_f32_16x16x32_bf16(af[i], bfm[j], acc[i][j], 0, 0, 0);
    }
  }

  // epilogue: C/D layout col=lane&15, row=(lane>>4)*4+reg
  #pragma unroll
  for (int i = 0; i < 4; ++i) {
    #pragma unroll
    for (int r = 0; r < 4; ++r) {
      int row = m0 + wm + i*16 + kgrp*4 + r;
      #pragma unroll
      for (int j = 0; j < 4; ++j) {
        int col = n0 + wn + j*16 + lrow;
        if constexpr (C_F32)
          ((float*)Cv)[(size_t)row * ldc + col] = acc[i][j][r];
        else
          ((unsigned short*)Cv)[(size_t)row * ldc + col] = f2bf(acc[i][j][r]);
      }
    }
  }
}

// ---------------------------------------------------------------------------
// Fused RoPE + V-transpose (one launch).
// Blocks [0,512): RoPE — thread (s,d) computes sincos ONCE, applies to all
// 40 rope'd heads (32 q + 8 k).  Blocks [512,1024): transpose V into vT.
// Disjoint regions (rope: Q+K, transpose reads V) — no ordering needed.
// ---------------------------------------------------------------------------
__global__ __launch_bounds__(256) void rope_transpose(
    unsigned short* __restrict__ qkv, const int* __restrict__ pos,
    unsigned short* __restrict__ vT) {
  __shared__ unsigned short tile[64][72];   // transpose staging (+8 pad)
  int b = blockIdx.x;
  if (b < 512) {
    int tid = b * 256 + threadIdx.x;   // 131072 = 2048 * 64
    int d   = tid & 63;
    int s   = tid >> 6;
    float inv = __expf((float)d * -0.17988946039016608f);  // 1e5^(-d/64)
    float ang = (float)pos[s] * inv;
    float sn, c;
    sincosf(ang, &sn, &c);
    unsigned short* base = qkv + (size_t)s * QKV_LD + d;
    #pragma unroll 4
    for (int head = 0; head < 40; ++head) {
      unsigned short* p = base + head * 128;
      float x1 = bf2f(p[0]);
      float x2 = bf2f(p[64]);
      p[0]  = f2bf(x1 * c - x2 * sn);
      p[64] = f2bf(x2 * c + x1 * sn);
    }
  } else {
    b -= 512;
    const int t  = threadIdx.x;
    const int s0 = (b & 31) * 64;
    const int c0 = (b >> 5) * 64;
    const int r  = t >> 3;          // 0..31
    const int cg = (t & 7) * 8;
    #pragma unroll
    for (int rr = 0; rr < 2; ++rr) {
      int row = rr * 32 + r;
      *(uint4*)&tile[row][cg] =
          *(const uint4*)(qkv + (size_t)(s0 + row) * QKV_LD + V_OFF + c0 + cg);
    }
    __syncthreads();
    #pragma unroll
    for (int rr = 0; rr < 2; ++rr) {
      int c = rr * 32 + r;
      unsigned short v[8];
      #pragma unroll
      for (int j = 0; j < 8; ++j) v[j] = tile[cg + j][c];
      *(uint4*)(vT + (size_t)(c0 + c) * SEQ + s0 + cg) = *(uint4*)v;
    }
  }
}

// ---------------------------------------------------------------------------
// Attention helpers (dual-Q-tile balanced kernel). Q is PRE-SCALED by
// log2(e)/sqrt(128), so scores are already in log2 domain.
// ---------------------------------------------------------------------------
__device__ inline bf16x8 scale_frag(bf16x8 v, float s) {
  bf16x8 r;
  #pragma unroll
  for (int j = 0; j < 8; ++j) r[j] = (__bf16)((float)v[j] * s);
  return r;
}

__device__ __forceinline__ void qk_softmax_tile(
    const bf16x8* qf, const unsigned short (*sK)[128],
    unsigned short (*sP)[72],
    f32x4* of, float* m_i, float* l_i,
    int lane, int wave, int dq, bool diag) {
  const int lrow = lane & 15;
  const int kgrp = lane >> 4;
  f32x4 st[4];
  #pragma unroll
  for (int tn = 0; tn < 4; ++tn)
    #pragma unroll
    for (int e = 0; e < 4; ++e) st[tn][e] = 0.f;
  #pragma unroll
  for (int ks = 0; ks < 4; ++ks) {
    #pragma unroll
    for (int tn = 0; tn < 4; ++tn) {
      int cgr = ks * 4 + kgrp;
      const bf16x8 kb = *(const bf16x8*)
          &sK[tn*16 + lrow][((cgr & 8) | ((cgr & 7) ^ (lrow & 7))) * 8];
      st[tn] = __builtin_amdgcn_mfma_f32_16x16x32_bf16(qf[ks], kb, st[tn], 0, 0, 0);
    }
  }
  float mrow[4] = {-1e30f, -1e30f, -1e30f, -1e30f};
  if (diag) {   // block-uniform branch: only the diagonal tile masks
    #pragma unroll
    for (int tn = 0; tn < 4; ++tn)
      #pragma unroll
      for (int r = 0; r < 4; ++r) {
        float s = st[tn][r];
        if (tn*16 + lrow > dq + r) s = -1e30f;
        st[tn][r] = s;
        mrow[r] = fmaxf(mrow[r], s);
      }
  } else {
    #pragma unroll
    for (int tn = 0; tn < 4; ++tn)
      #pragma unroll
      for (int r = 0; r < 4; ++r)
        mrow[r] = fmaxf(mrow[r], st[tn][r]);
  }
  #pragma unroll
  for (int r = 0; r < 4; ++r)
    #pragma unroll
    for (int off = 1; off < 16; off <<= 1)
      mrow[r] = fmaxf(mrow[r], __shfl_xor(mrow[r], off, 16));
  float alpha[4];
  #pragma unroll
  for (int r = 0; r < 4; ++r) {
    float mnew = fmaxf(m_i[r], mrow[r]);
    alpha[r] = exp2f(m_i[r] - mnew);
    m_i[r] = mnew;
  }
  float rsum[4] = {0.f, 0.f, 0.f, 0.f};
  #pragma unroll
  for (int tn = 0; tn < 4; ++tn)
    #pragma unroll
    for (int r = 0; r < 4; ++r) {
      float pr = exp2f(st[tn][r] - m_i[r]);
      rsum[r] += pr;
      sP[wave*16 + kgrp*4 + r][tn*16 + lrow] = f2bf(pr);
    }
  #pragma unroll
  for (int r = 0; r < 4; ++r) {
    #pragma unroll
    for (int off = 1; off < 16; off <<= 1)
      rsum[r] += __shfl_xor(rsum[r], off, 16);
    l_i[r] = l_i[r] * alpha[r] + rsum[r];
  }
  #pragma unroll
  for (int tt = 0; tt < 8; ++tt)
    #pragma unroll
    for (int r = 0; r < 4; ++r)
      of[tt][r] *= alpha[r];
}

__device__ __forceinline__ void pv_tile(
    const unsigned short (*sP)[72], const unsigned short (*sVt)[64],
    f32x4* of, int lane, int wave) {
  const int lrow = lane & 15;
  const int kgrp = lane >> 4;
  #pragma unroll
  for (int ks = 0; ks < 2; ++ks) {
    const bf16x8 pa = *(const bf16x8*)&sP[wave*16 + lrow][ks*32 + kgrp*8];
    #pragma unroll
    for (int tt = 0; tt < 8; ++tt) {
      int cgr = ks * 4 + kgrp;
      const bf16x8 vb = *(const bf16x8*)
          &sVt[tt*16 + lrow][(cgr ^ (lrow & 7)) * 8];
      of[tt] = __builtin_amdgcn_mfma_f32_16x16x32_bf16(pa, vb, of[tt], 0, 0, 0);
    }
  }
}

// ---------------------------------------------------------------------------
// Balanced causal flash attention, GQA. Block p of 16 handles Q-tiles
// p (low) and 31-p (high); KV staged once per key-tile, shared. O written
// in-place into the Q region of qkv.
// ---------------------------------------------------------------------------
__global__ __launch_bounds__(256, 2) void attn_fwd2(
    unsigned short* __restrict__ qkv, const unsigned short* __restrict__ vT) {
  __shared__ __align__(16) unsigned short sK[64][128];   // [key][d] swizzled
  __shared__ __align__(16) unsigned short sVt[128][64];  // [d][key] swizzled
  __shared__ __align__(16) unsigned short sP[128][72];   // rows 0-63 hi, 64-127 lo

  const int t    = threadIdx.x;
  const int wave = t >> 6;
  const int lane = t & 63;
  const int lrow = lane & 15;
  const int kgrp = lane >> 4;
  const int p    = blockIdx.x;          // 0..15
  const int h    = blockIdx.y;
  const int kvh  = h >> 2;
  const int qLo  = p * 64;
  const int qHi  = (31 - p) * 64;
  const int nTiles = 32 - p;            // key-tiles for high Q-tile
  const int nDual  = p + 1;             // key-tiles where low tile is active

  const float scale2 = 0.12751743f;     // log2(e)/sqrt(128)
  bf16x8 qfH[4], qfL[4];
  {
    const unsigned short* qr =
        qkv + (size_t)(qHi + wave*16 + lrow) * QKV_LD + h * HEADD;
    #pragma unroll
    for (int ks = 0; ks < 4; ++ks)
      qfH[ks] = scale_frag(*(const bf16x8*)(qr + ks*32 + kgrp*8), scale2);
    qr = qkv + (size_t)(qLo + wave*16 + lrow) * QKV_LD + h * HEADD;
    #pragma unroll
    for (int ks = 0; ks < 4; ++ks)
      qfL[ks] = scale_frag(*(const bf16x8*)(qr + ks*32 + kgrp*8), scale2);
  }

  f32x4 ofH[8], ofL[8];
  float mH[4], lH[4], mL[4], lL[4];
  #pragma unroll
  for (int tt = 0; tt < 8; ++tt)
    #pragma unroll
    for (int e = 0; e < 4; ++e) { ofH[tt][e] = 0.f; ofL[tt][e] = 0.f; }
  #pragma unroll
  for (int r = 0; r < 4; ++r) { mH[r] = -1e30f; lH[r] = 0.f; mL[r] = -1e30f; lL[r] = 0.f; }

  for (int kt = 0; kt < nTiles; ++kt) {
    const int k0 = kt * 64;
    __syncthreads();
    // stage K tile (64x128): 16 chunks of 4 rows (1 KB each)
    #pragma unroll
    for (int c = 0; c < 4; ++c) {
      int cc   = wave * 4 + c;
      int grow = cc * 4 + (lane >> 4);
      int slot = lane & 15;
      int cg   = (slot & 8) | ((slot & 7) ^ (grow & 7));
      __builtin_amdgcn_global_load_lds(
          (const __attribute__((address_space(1))) unsigned int*)
              (qkv + (size_t)(k0 + grow) * QKV_LD + K_OFF + kvh*HEADD + cg*8),
          (__attribute__((address_space(3))) unsigned int*)&sK[cc*4][0],
          16, 0, 0);
    }
    // stage V^T tile (128x64): 16 chunks of 8 rows
    #pragma unroll
    for (int c = 0; c < 4; ++c) {
      int cc   = wave * 4 + c;
      int grow = cc * 8 + (lane >> 3);
      int slot = lane & 7;
      int cg   = slot ^ (grow & 7);
      __builtin_amdgcn_global_load_lds(
          (const __attribute__((address_space(1))) unsigned int*)
              (vT + (size_t)(kvh*HEADD + grow) * SEQ + k0 + cg*8),
          (__attribute__((address_space(3))) unsigned int*)&sVt[cc*8][0],
          16, 0, 0);
    }
    __syncthreads();

    const bool dual = (kt < nDual);
    qk_softmax_tile(qfH, sK, &sP[0],  ofH, mH, lH, lane, wave,
                    qHi + wave*16 + kgrp*4 - k0, k0 == qHi);
    if (dual)
      qk_softmax_tile(qfL, sK, &sP[64], ofL, mL, lL, lane, wave,
                      qLo + wave*16 + kgrp*4 - k0, k0 == qLo);
    __syncthreads();
    pv_tile(&sP[0], sVt, ofH, lane, wave);
    if (dual) pv_tile(&sP[64], sVt, ofL, lane, wave);
  }

  // epilogue: normalize, write both tiles in-place into the Q region
  #pragma unroll
  for (int r = 0; r < 4; ++r) {
    float invH = 1.f / lH[r];
    float invL = 1.f / lL[r];
    int rowH = qHi + wave*16 + kgrp*4 + r;
    int rowL = qLo + wave*16 + kgrp*4 + r;
    #pragma unroll
    for (int tt = 0; tt < 8; ++tt) {
      qkv[(size_t)rowH * QKV_LD + h*HEADD + tt*16 + lrow] = f2bf(ofH[tt][r] * invH);
      qkv[(size_t)rowL * QKV_LD + h*HEADD + tt*16 + lrow] = f2bf(ofL[tt][r] * invL);
    }
  }
}

// ---------------------------------------------------------------------------
// Fallback path kernels (small-ws): rope-only + single-tile attention
// ---------------------------------------------------------------------------
__global__ __launch_bounds__(256) void rope_kernel(
    unsigned short* __restrict__ qkv, const int* __restrict__ pos) {
  int tid  = blockIdx.x * 256 + threadIdx.x;
  int d    = tid & 63;
  int s    = tid >> 6;
  if (s >= SEQ) return;
  float inv = __expf((float)d * -0.17988946039016608f);
  float ang = (float)pos[s] * inv;
  float sn, c;
  sincosf(ang, &sn, &c);
  unsigned short* base = qkv + (size_t)s * QKV_LD + d;
  #pragma unroll 4
  for (int head = 0; head < 40; ++head) {
    unsigned short* p = base + head * 128;
    float x1 = bf2f(p[0]);
    float x2 = bf2f(p[64]);
    p[0]  = f2bf(x1 * c - x2 * sn);
    p[64] = f2bf(x2 * c + x1 * sn);
  }
}

__global__ __launch_bounds__(256, 2) void attn_fwd(
    unsigned short* __restrict__ qkv) {
  __shared__ __align__(16) unsigned short sK[64][136];
  __shared__ __align__(16) unsigned short sVt[128][72];
  __shared__ __align__(16) unsigned short sP[64][72];

  const int t    = threadIdx.x;
  const int wave = t >> 6;
  const int lane = t & 63;
  const int lrow = lane & 15;
  const int kgrp = lane >> 4;
  const int q0   = blockIdx.x * 64;
  const int h    = blockIdx.y;
  const int kvh  = h >> 2;

  bf16x8 qf[4];
  {
    const unsigned short* qrow =
        qkv + (size_t)(q0 + wave*16 + lrow) * QKV_LD + h * HEADD;
    #pragma unroll
    for (int ks = 0; ks < 4; ++ks)
      qf[ks] = *(const bf16x8*)(qrow + ks*32 + kgrp*8);
  }

  f32x4 of[8];
  #pragma unroll
  for (int tt = 0; tt < 8; ++tt)
    #pragma unroll
    for (int e = 0; e < 4; ++e) of[tt][e] = 0.f;
  float m_i[4], l_i[4];
  #pragma unroll
  for (int r = 0; r < 4; ++r) { m_i[r] = -1e30f; l_i[r] = 0.f; }

  const float scale = 0.08838834764831845f;

  for (int k0 = 0; k0 <= q0; k0 += 64) {
    __syncthreads();
    {
      int krow = t >> 4;
      int kcol = (t & 15) * 8;
      #pragma unroll
      for (int r = 0; r < 4; ++r)
        *(uint4*)&sK[r*16 + krow][kcol] =
            *(const uint4*)(qkv + (size_t)(k0 + r*16 + krow) * QKV_LD + K_OFF + kvh*HEADD + kcol);
      int vrow = t & 15;
      int vcol = (t >> 4) * 8;
      #pragma unroll
      for (int r = 0; r < 4; ++r) {
        uint4 v = *(const uint4*)(qkv + (size_t)(k0 + r*16 + vrow) * QKV_LD + V_OFF + kvh*HEADD + vcol);
        const unsigned short* pv = (const unsigned short*)&v;
        #pragma unroll
        for (int j = 0; j < 8; ++j)
          sVt[vcol + j][r*16 + vrow] = pv[j];
      }
    }
    __syncthreads();

    f32x4 st[4];
    #pragma unroll
    for (int tn = 0; tn < 4; ++tn)
      #pragma unroll
      for (int e = 0; e < 4; ++e) st[tn][e] = 0.f;
    #pragma unroll
    for (int ks = 0; ks < 4; ++ks)
      #pragma unroll
      for (int tn = 0; tn < 4; ++tn) {
        bf16x8 kb = *(const bf16x8*)&sK[tn*16 + lrow][ks*32 + kgrp*8];
        st[tn] = __builtin_amdgcn_mfma_f32_16x16x32_bf16(qf[ks], kb, st[tn], 0, 0, 0);
      }

    float mrow[4];
    #pragma unroll
    for (int r = 0; r < 4; ++r) mrow[r] = -1e30f;
    const int qrow_base = q0 + wave*16 + kgrp*4;
    #pragma unroll
    for (int tn = 0; tn < 4; ++tn) {
      int kcol = k0 + tn*16 + lrow;
      #pragma unroll
      for (int r = 0; r < 4; ++r) {
        float s = st[tn][r] * scale;
        if (kcol > qrow_base + r) s = -1e30f;
        st[tn][r] = s;
        mrow[r] = fmaxf(mrow[r], s);
      }
    }
    #pragma unroll
    for (int r = 0; r < 4; ++r)
      #pragma unroll
      for (int off = 1; off < 16; off <<= 1)
        mrow[r] = fmaxf(mrow[r], __shfl_xor(mrow[r], off, 16));

    float alpha[4];
    #pragma unroll
    for (int r = 0; r < 4; ++r) {
      float mnew = fmaxf(m_i[r], mrow[r]);
      alpha[r] = __expf(m_i[r] - mnew);
      m_i[r] = mnew;
    }

    float rsum[4] = {0.f, 0.f, 0.f, 0.f};
    #pragma unroll
    for (int tn = 0; tn < 4; ++tn)
      #pragma unroll
      for (int r = 0; r < 4; ++r) {
        float pr = __expf(st[tn][r] - m_i[r]);
        rsum[r] += pr;
        sP[wave*16 + kgrp*4 + r][tn*16 + lrow] = f2bf(pr);
      }
    #pragma unroll
    for (int r = 0; r < 4; ++r) {
      #pragma unroll
      for (int off = 1; off < 16; off <<= 1)
        rsum[r] += __shfl_xor(rsum[r], off, 16);
      l_i[r] = l_i[r] * alpha[r] + rsum[r];
    }
    #pragma unroll
    for (int tt = 0; tt < 8; ++tt)
      #pragma unroll
      for (int r = 0; r < 4; ++r)
        of[tt][r] *= alpha[r];

    __syncthreads();

    #pragma unroll
    for (int ks = 0; ks < 2; ++ks) {
      bf16x8 pa = *(const bf16x8*)&sP[wave*16 + lrow][ks*32 + kgrp*8];
      #pragma unroll
      for (int tt = 0; tt < 8; ++tt) {
        bf16x8 vb = *(const bf16x8*)&sVt[tt*16 + lrow][ks*32 + kgrp*8];
        of[tt] = __builtin_amdgcn_mfma_f32_16x16x32_bf16(pa, vb, of[tt], 0, 0, 0);
      }
    }
  }

  #pragma unroll
  for (int r = 0; r < 4; ++r) {
    int row = q0 + wave*16 + kgrp*4 + r;
    float inv = 1.f / l_i[r];
    #pragma unroll
    for (int tt = 0; tt < 8; ++tt)
      qkv[(size_t)row * QKV_LD + h*HEADD + tt*16 + lrow] = f2bf(of[tt][r] * inv);
  }
}

// ---------------------------------------------------------------------------
extern "C" void kernel_launch(void* const* d_in, const int* in_sizes, int n_in,
                              void* d_out, int out_size, void* d_ws, size_t ws_size,
                              hipStream_t stream) {
  const float* hs    = (const float*)d_in[0];   // f32 [2048][4096]
  const int*   pos   = (const int*)d_in[1];     // int32 [2048]
  const float* w_qkv = (const float*)d_in[2];   // f32 [6144][4096]
  const float* w_o   = (const float*)d_in[3];   // f32 [4096][4096]
  float*       out   = (float*)d_out;           // f32 [2048][4096]

  const size_t N_QKV  = (size_t)SEQ * QKV_LD;
  const size_t N_HS   = (size_t)SEQ * HDIM;
  const size_t N_WQKV = (size_t)QKV_LD * HDIM;
  const size_t N_WO   = (size_t)HDIM * HDIM;

  unsigned short* qkv = (unsigned short*)d_ws;  // bf16 [2048][6144]

  const size_t full_ws = (N_QKV + N_HS + N_WQKV + N_WO) * 2;  // ~126 MB

  if (ws_size >= full_ws) {
    unsigned short* hs_b   = qkv + N_QKV;
    unsigned short* wqkv_b = hs_b + N_HS;
    unsigned short* wo_b   = wqkv_b + N_WQKV;
    // vT reuses hs_b (dead after the QKV GEMM)
    unsigned short* vT     = hs_b;

    cvt_all<<<2048, 256, 0, stream>>>(hs, w_qkv, w_o, hs_b,
                                      (int)(N_HS / 8), (int)(N_WQKV / 8),
                                      (int)(N_WO / 8));
    gemm_bt<1, 1, 0><<<dim3(SEQ/128, QKV_LD/128), 256, 0, stream>>>(
        hs_b, wqkv_b, qkv, HDIM, HDIM, HDIM, QKV_LD);
    rope_transpose<<<1024, 256, 0, stream>>>(qkv, pos, vT);
    attn_fwd2<<<dim3(16, NHEADS), 256, 0, stream>>>(qkv, vT);
    gemm_bt<1, 1, 1><<<dim3(SEQ/128, HDIM/128), 256, 0, stream>>>(
        qkv, wo_b, out, HDIM, QKV_LD, HDIM, HDIM);
  } else {
    // fallback: inline f32->bf16 packing during staging
    gemm_bt<0, 0, 0><<<dim3(SEQ/128, QKV_LD/128), 256, 0, stream>>>(
        hs, w_qkv, qkv, HDIM, HDIM, HDIM, QKV_LD);
    rope_kernel<<<SEQ * 64 / 256, 256, 0, stream>>>(qkv, pos);
    attn_fwd<<<dim3(SEQ/64, NHEADS), 256, 0, stream>>>(qkv);
    gemm_bt<1, 0, 1><<<dim3(SEQ/128, HDIM/128), 256, 0, stream>>>(
        qkv, w_o, out, HDIM, QKV_LD, HDIM, HDIM);
  }
}